// Round 12
// baseline (161.936 us; speedup 1.0000x reference)
//
#include <hip/hip_runtime.h>
#include <hip/hip_bf16.h>
#include <stdint.h>

// Problem constants
#define B_ 2
#define N_ 2048
#define DIM_ 1024
#define H_ 16
#define HD_ 64

typedef __attribute__((ext_vector_type(8))) short short8;
typedef __attribute__((ext_vector_type(4))) float f32x4;
typedef __attribute__((ext_vector_type(16))) float f32x16;

#define LOG2E_ 1.4426950408889634f
#define SBF_ (0.125f * LOG2E_)

__device__ __forceinline__ unsigned short f2bf(float f) {
  __bf16 h = (__bf16)f;
  return __builtin_bit_cast(unsigned short, h);
}

__device__ __forceinline__ void gload_lds16(const void* g, void* l) {
  __builtin_amdgcn_global_load_lds(
      (const __attribute__((address_space(1))) unsigned int*)g,
      (__attribute__((address_space(3))) unsigned int*)l,
      16, 0, 0);
}

// ---------------- merged f32 -> bf16 conversion ----------------
#define XN4_ 1048576   // (2*2048*1024)/4
#define WQ4_ 786432    // (3*1024*1024)/4
__global__ __launch_bounds__(256) void cvt_all_kernel(
    const float4* __restrict__ x, const float4* __restrict__ wq,
    const float4* __restrict__ wp,
    ushort4* __restrict__ xb, ushort4* __restrict__ wqb, ushort4* __restrict__ wpb) {
  int i = blockIdx.x * 256 + threadIdx.x;
  const float4* src;
  ushort4* dst;
  if (i < XN4_) {
    src = x + i; dst = xb + i;
  } else if (i < XN4_ + WQ4_) {
    src = wq + (i - XN4_); dst = wqb + (i - XN4_);
  } else {
    src = wp + (i - XN4_ - WQ4_); dst = wpb + (i - XN4_ - WQ4_);
  }
  float4 v = *src;
  ushort4 o;
  o.x = f2bf(v.x); o.y = f2bf(v.y); o.z = f2bf(v.z); o.w = f2bf(v.w);
  *dst = o;
}

// ---------------- 128x128 bf16 GEMM mainloop, SWAPPED operands ----------------
__device__ __forceinline__ void gemm128_mainloop(
    const ushort* __restrict__ A, const ushort* __restrict__ Bw, int K,
    int bm, int bn, ushort* As, ushort* Bs, f32x4 acc[4][4]) {
  const int tid = threadIdx.x;
  const int lane = tid & 63;
  const int w = tid >> 6, wr = w >> 1, wc = w & 1;
  const int fr = lane & 15, fq = lane >> 4;
  const int srow = tid >> 3, scol = (tid & 7) * 8;

  const ushort* Ag = A + (size_t)(bm * 128 + srow) * K + scol;
  const ushort* Bg = Bw + (size_t)(bn * 128 + srow) * K + scol;
  ushort* Asd = As + tid * 8;
  ushort* Bsd = Bs + tid * 8;

  for (int kt = 0; kt < K; kt += 64) {
    __syncthreads();
#pragma unroll
    for (int c = 0; c < 4; ++c) {
      gload_lds16(Ag + (size_t)(c * 32) * K + kt, Asd + c * 2048);
      gload_lds16(Bg + (size_t)(c * 32) * K + kt, Bsd + c * 2048);
    }
    __syncthreads();

    short8 af[2][4], bf[2][4];
#pragma unroll
    for (int kk = 0; kk < 2; ++kk) {
#pragma unroll
      for (int mi = 0; mi < 4; ++mi)
        af[kk][mi] = *(const short8*)&As[(wr * 64 + mi * 16 + fr) * 64 + kk * 32 + fq * 8];
#pragma unroll
      for (int ni = 0; ni < 4; ++ni)
        bf[kk][ni] = *(const short8*)&Bs[(wc * 64 + ni * 16 + fr) * 64 + kk * 32 + fq * 8];
    }
#pragma unroll
    for (int kk = 0; kk < 2; ++kk)
#pragma unroll
      for (int mi = 0; mi < 4; ++mi)
#pragma unroll
        for (int ni = 0; ni < 4; ++ni)
          acc[mi][ni] = __builtin_amdgcn_mfma_f32_16x16x32_bf16(
              bf[kk][ni], af[kk][mi], acc[mi][ni], 0, 0, 0);  // swapped
  }
}

// ---------------- QKV GEMM: packed q/k epilogue; q pre-scaled; V^T ----------------
__global__ __launch_bounds__(256) void gemm_qkv_kernel(
    const ushort* __restrict__ xb, const ushort* __restrict__ wqkv,
    const float* __restrict__ bqkv,
    ushort* __restrict__ qo, ushort* __restrict__ ko, ushort* __restrict__ vo) {
  __shared__ ushort As[128 * 64];
  __shared__ ushort Bs[128 * 64];
  f32x4 acc[4][4] = {};
  const int bn = blockIdx.x, bm = blockIdx.y;
  gemm128_mainloop(xb, wqkv, DIM_, bm, bn, As, Bs, acc);

  const int tid = threadIdx.x, lane = tid & 63;
  const int w = tid >> 6, wr = w >> 1, wc = w & 1;
  const int fr = lane & 15, fq = lane >> 4;
#pragma unroll
  for (int mi = 0; mi < 4; ++mi) {
    int ng = bm * 128 + wr * 64 + mi * 16 + fr;  // token index [0,4096)
    int b = ng >> 11, n = ng & 2047;
#pragma unroll
    for (int ni = 0; ni < 4; ++ni) {
      int colb = bn * 128 + wc * 64 + ni * 16 + fq * 4;  // 4-aligned output col
      float4 b4 = *(const float4*)&bqkv[colb];
      int i3 = colb >> 10, h = (colb >> 6) & 15, hdq = colb & 63;
      float v0 = acc[mi][ni][0] + b4.x;
      float v1 = acc[mi][ni][1] + b4.y;
      float v2 = acc[mi][ni][2] + b4.z;
      float v3 = acc[mi][ni][3] + b4.w;
      if (i3 == 2) {
        // V^T [bh][d][N]
        size_t base = ((size_t)((b * H_ + h) * HD_ + hdq)) * N_ + n;
        vo[base]          = f2bf(v0);
        vo[base + N_]     = f2bf(v1);
        vo[base + 2 * N_] = f2bf(v2);
        vo[base + 3 * N_] = f2bf(v3);
      } else {
        // q is pre-scaled by 0.125*log2e so attn exp2 needs no multiply
        const float s = (i3 == 0) ? SBF_ : 1.0f;
        ushort* base = (i3 == 0) ? qo : ko;
        ushort4 o;
        o.x = f2bf(v0 * s); o.y = f2bf(v1 * s);
        o.z = f2bf(v2 * s); o.w = f2bf(v3 * s);
        *(ushort4*)&base[((size_t)(b * H_ + h) * N_ + n) * HD_ + hdq] = o;
      }
    }
  }
}

// ---------------- Proj GEMM: float4 output + bias ----------------
__global__ __launch_bounds__(256) void gemm_proj_kernel(
    const ushort* __restrict__ ao, const ushort* __restrict__ wp,
    const float* __restrict__ bp, float* __restrict__ out) {
  __shared__ ushort As[128 * 64];
  __shared__ ushort Bs[128 * 64];
  f32x4 acc[4][4] = {};
  const int bn = blockIdx.x, bm = blockIdx.y;
  gemm128_mainloop(ao, wp, DIM_, bm, bn, As, Bs, acc);

  const int tid = threadIdx.x, lane = tid & 63;
  const int w = tid >> 6, wr = w >> 1, wc = w & 1;
  const int fr = lane & 15, fq = lane >> 4;
#pragma unroll
  for (int mi = 0; mi < 4; ++mi) {
    int mg = bm * 128 + wr * 64 + mi * 16 + fr;
#pragma unroll
    for (int ni = 0; ni < 4; ++ni) {
      int colb = bn * 128 + wc * 64 + ni * 16 + fq * 4;
      float4 b4 = *(const float4*)&bp[colb];
      float4 o;
      o.x = acc[mi][ni][0] + b4.x;
      o.y = acc[mi][ni][1] + b4.y;
      o.z = acc[mi][ni][2] + b4.z;
      o.w = acc[mi][ni][3] + b4.w;
      *(float4*)&out[(size_t)mg * DIM_ + colb] = o;
    }
  }
}

// ---------------- Flash attention v7: split-KV, V direct from L2 ----------------
// 1024 blocks, 4 waves = {q-group 0,1} x {kv-half 0,1}; 64 q-rows/block.
// K staged per-half in LDS (dbuf); V fragments loaded straight from L2 (V^T
// layout makes each PV fragment one 16B load). Static softmax -> cross-half
// combine is exact: O = (O0+O1)/(l0+l1), via 16KB LDS reuse at block end.
__global__ __launch_bounds__(256, 3) void attn_kernel(
    const ushort* __restrict__ Qg, const ushort* __restrict__ Kg,
    const ushort* __restrict__ Vtg, const float* __restrict__ rel,
    ushort* __restrict__ outb) {
  __shared__ alignas(16) unsigned char smem[32768];
  ushort* KsB = (ushort*)smem;  // [half][buf][64*64] (swizzled K tiles)

  const int bid = blockIdx.x;               // [0,1024)
  const int xcd = bid & 7, idx = bid >> 3;  // idx in [0,128)
  const int bh = xcd * 4 + (idx >> 5);      // 4 bh per XCD
  const int q0 = (idx & 31) * 64;
  const int h = bh & 15;
  const int tid = threadIdx.x, lane = tid & 63, w = tid >> 6;
  const int ql = lane & 31, hi = lane >> 5;
  const int qg = w & 1, half = w >> 1;      // q-group, kv-half

  // bias (exp2-domain) in the MFMA C-operand: key%8 = (reg&3)+4*hi, q%8 = ql&7
  f32x16 biasC;
  {
    float b0 = rel[h * 64 + (ql & 7) * 8 + 0 + 4 * hi] * LOG2E_;
    float b1 = rel[h * 64 + (ql & 7) * 8 + 1 + 4 * hi] * LOG2E_;
    float b2 = rel[h * 64 + (ql & 7) * 8 + 2 + 4 * hi] * LOG2E_;
    float b3 = rel[h * 64 + (ql & 7) * 8 + 3 + 4 * hi] * LOG2E_;
#pragma unroll
    for (int z = 0; z < 16; z += 4) {
      biasC[z] = b0; biasC[z + 1] = b1; biasC[z + 2] = b2; biasC[z + 3] = b3;
    }
  }

  // Q B-fragments (q pre-scaled by 0.125*log2e at the producer)
  const ushort* qrow = Qg + ((size_t)bh * N_ + q0 + qg * 32 + ql) * HD_;
  short8 qf[4];
#pragma unroll
  for (int kk = 0; kk < 4; ++kk)
    qf[kk] = *(const short8*)&qrow[kk * 16 + hi * 8];

  // V^T row bases for the two db output blocks (direct L2 loads)
  const ushort* Vb0 = Vtg + ((size_t)(bh * HD_ + ql)) * N_;
  const ushort* Vb1 = Vtg + ((size_t)(bh * HD_ + 32 + ql)) * N_;

  float l = 0.f;
  f32x16 oacc[2] = {};
  f32x16 S[2];

  int kcol[4];  // swizzled LDS col for kf reads
#pragma unroll
  for (int kk = 0; kk < 4; ++kk)
    kcol[kk] = (kk * 16 + hi * 8) ^ ((ql & 7) << 3);

  // stage K tile (half*16 + t) for both halves; 128 threads per half-tile
#define STAGE_K(t, bb)                                                              \
  {                                                                                 \
    const int hf = tid >> 7, r = tid & 127;                                         \
    const size_t krow = (size_t)bh * N_ + (size_t)(hf * 16 + (t)) * 64;             \
    _Pragma("unroll") for (int c = 0; c < 4; ++c)                                   \
        gload_lds16(Kg + (krow + c * 16 + (r >> 3)) * HD_ +                         \
                        (((r & 7) * 8) ^ (((r >> 3) & 7) << 3)),                    \
                    &KsB[(hf * 2 + (bb)) * 4096 + c * 1024 + r * 8]);               \
  }

  STAGE_K(0, 0);
  __syncthreads();

#pragma unroll 2
  for (int t = 0; t < 16; ++t) {
    const int cur = t & 1;
    const int kv0 = (half * 16 + t) * 64;

    // V fragments for this tile: direct global (L2-resident), hidden under QKT
    short8 vf[4][2];
#pragma unroll
    for (int kk = 0; kk < 4; ++kk) {
      vf[kk][0] = *(const short8*)&Vb0[kv0 + kk * 16 + hi * 8];
      vf[kk][1] = *(const short8*)&Vb1[kv0 + kk * 16 + hi * 8];
    }

    if (t < 15) STAGE_K(t + 1, cur ^ 1);

    // S^T = K @ Q^T with C = bias
    const ushort* K_ = KsB + (half * 2 + cur) * 4096;
    S[0] = biasC;
    S[1] = biasC;
    __builtin_amdgcn_s_setprio(1);
#pragma unroll
    for (int kk = 0; kk < 4; ++kk) {
      short8 kf0 = *(const short8*)&K_[ql * 64 + kcol[kk]];
      short8 kf1 = *(const short8*)&K_[(32 + ql) * 64 + kcol[kk]];
      S[0] = __builtin_amdgcn_mfma_f32_32x32x16_bf16(kf0, qf[kk], S[0], 0, 0, 0);
      S[1] = __builtin_amdgcn_mfma_f32_32x32x16_bf16(kf1, qf[kk], S[1], 0, 0, 0);
    }
    __builtin_amdgcn_s_setprio(0);

    // static softmax + in-register P exchange
    float rs_[4] = {0.f, 0.f, 0.f, 0.f};
    uint32_t c[2][8];
#pragma unroll
    for (int blk = 0; blk < 2; ++blk) {
#pragma unroll
      for (int i = 0; i < 8; ++i) {
        float pa = __builtin_amdgcn_exp2f(S[blk][2 * i]);
        float pb = __builtin_amdgcn_exp2f(S[blk][2 * i + 1]);
        rs_[i & 3] += pa + pb;
        c[blk][i] = ((uint32_t)f2bf(pb) << 16) | f2bf(pa);
      }
    }
    float rs = (rs_[0] + rs_[1]) + (rs_[2] + rs_[3]);
    rs += __shfl_xor(rs, 32, 64);
    l += rs;
#pragma unroll
    for (int blk = 0; blk < 2; ++blk) {
      asm("v_permlane32_swap_b32 %0, %1" : "+v"(c[blk][0]), "+v"(c[blk][2]));
      asm("v_permlane32_swap_b32 %0, %1" : "+v"(c[blk][1]), "+v"(c[blk][3]));
      asm("v_permlane32_swap_b32 %0, %1" : "+v"(c[blk][4]), "+v"(c[blk][6]));
      asm("v_permlane32_swap_b32 %0, %1" : "+v"(c[blk][5]), "+v"(c[blk][7]));
    }

    // O^T += V^T @ P^T (vf from registers)
    __builtin_amdgcn_s_setprio(1);
#pragma unroll
    for (int kk = 0; kk < 4; ++kk) {
      union { uint32_t u[4]; short8 s8; } pb_;
      pb_.u[0] = c[kk >> 1][(kk & 1) * 4 + 0];
      pb_.u[1] = c[kk >> 1][(kk & 1) * 4 + 1];
      pb_.u[2] = c[kk >> 1][(kk & 1) * 4 + 2];
      pb_.u[3] = c[kk >> 1][(kk & 1) * 4 + 3];
      oacc[0] = __builtin_amdgcn_mfma_f32_32x32x16_bf16(vf[kk][0], pb_.s8, oacc[0], 0, 0, 0);
      oacc[1] = __builtin_amdgcn_mfma_f32_32x32x16_bf16(vf[kk][1], pb_.s8, oacc[1], 0, 0, 0);
    }
    __builtin_amdgcn_s_setprio(0);
    __syncthreads();
  }
#undef STAGE_K

  // ---- cross-half combine (exact under static softmax) ----
  float* Olds = (float*)smem;            // [2][32][64] f32 (16 KB, reuses K space)
  float* Llds = (float*)(smem + 16384);  // [2][32]
  if (half == 1) {
#pragma unroll
    for (int db = 0; db < 2; ++db)
#pragma unroll
      for (int g = 0; g < 4; ++g) {
        f32x4 v;
        v[0] = oacc[db][4 * g + 0]; v[1] = oacc[db][4 * g + 1];
        v[2] = oacc[db][4 * g + 2]; v[3] = oacc[db][4 * g + 3];
        *(f32x4*)&Olds[(qg * 32 + ql) * 64 + db * 32 + 8 * g + 4 * hi] = v;
      }
    Llds[qg * 32 + ql] = l;
  }
  __syncthreads();
  if (half == 0) {
    const int b = bh >> 4;
    float l2 = Llds[qg * 32 + ql];
    float invl = 1.0f / (l + l2);
    size_t rowbase = ((size_t)(b * N_ + q0 + qg * 32 + ql)) * DIM_ + h * HD_;
#pragma unroll
    for (int db = 0; db < 2; ++db)
#pragma unroll
      for (int g = 0; g < 4; ++g) {
        f32x4 v = *(const f32x4*)&Olds[(qg * 32 + ql) * 64 + db * 32 + 8 * g + 4 * hi];
        ushort4 o;
        o.x = f2bf((oacc[db][4 * g + 0] + v[0]) * invl);
        o.y = f2bf((oacc[db][4 * g + 1] + v[1]) * invl);
        o.z = f2bf((oacc[db][4 * g + 2] + v[2]) * invl);
        o.w = f2bf((oacc[db][4 * g + 3] + v[3]) * invl);
        *(ushort4*)&outb[rowbase + db * 32 + 8 * g + 4 * hi] = o;
      }
  }
}

// ---------------- host launcher ----------------
extern "C" void kernel_launch(void* const* d_in, const int* in_sizes, int n_in,
                              void* d_out, int out_size, void* d_ws, size_t ws_size,
                              hipStream_t stream) {
  const float* x      = (const float*)d_in[0];
  const float* w_qkv  = (const float*)d_in[1];
  const float* b_qkv  = (const float*)d_in[2];
  const float* w_proj = (const float*)d_in[3];
  const float* b_proj = (const float*)d_in[4];
  const float* rel    = (const float*)d_in[5];

  char* ws = (char*)d_ws;
  ushort* xb     = (ushort*)(ws + 0);
  ushort* wqkvb  = (ushort*)(ws + 8388608);
  ushort* wprojb = (ushort*)(ws + 14680064);
  ushort* qb     = (ushort*)(ws + 16777216);
  ushort* kb     = (ushort*)(ws + 25165824);
  ushort* vb     = (ushort*)(ws + 33554432);   // V^T [32][64][2048]
  ushort* aob    = (ushort*)(ws + 41943040);
  (void)in_sizes; (void)n_in; (void)out_size; (void)ws_size;

  cvt_all_kernel<<<8192, 256, 0, stream>>>(
      (const float4*)x, (const float4*)w_qkv, (const float4*)w_proj,
      (ushort4*)xb, (ushort4*)wqkvb, (ushort4*)wprojb);

  gemm_qkv_kernel<<<dim3(24, 32), 256, 0, stream>>>(xb, wqkvb, b_qkv, qb, kb, vb);
  attn_kernel<<<1024, 256, 0, stream>>>(qb, kb, vb, rel, aob);
  gemm_proj_kernel<<<dim3(8, 32), 256, 0, stream>>>(aob, wprojb, b_proj, (float*)d_out);
}

// Round 13
// 139.267 us; speedup vs baseline: 1.1628x; 1.1628x over previous
//
#include <hip/hip_runtime.h>
#include <hip/hip_bf16.h>
#include <stdint.h>

// Problem constants
#define B_ 2
#define N_ 2048
#define DIM_ 1024
#define H_ 16
#define HD_ 64
#define NT_ 32  // N_/64 kv tiles

typedef __attribute__((ext_vector_type(8))) short short8;
typedef __attribute__((ext_vector_type(4))) float f32x4;
typedef __attribute__((ext_vector_type(16))) float f32x16;

#define LOG2E_ 1.4426950408889634f
#define SBF_ (0.125f * LOG2E_)

__device__ __forceinline__ unsigned short f2bf(float f) {
  __bf16 h = (__bf16)f;
  return __builtin_bit_cast(unsigned short, h);
}

__device__ __forceinline__ void gload_lds16(const void* g, void* l) {
  __builtin_amdgcn_global_load_lds(
      (const __attribute__((address_space(1))) unsigned int*)g,
      (__attribute__((address_space(3))) unsigned int*)l,
      16, 0, 0);
}

// ---------------- merged f32 -> bf16 conversion ----------------
#define XN4_ 1048576   // (2*2048*1024)/4
#define WQ4_ 786432    // (3*1024*1024)/4
__global__ __launch_bounds__(256) void cvt_all_kernel(
    const float4* __restrict__ x, const float4* __restrict__ wq,
    const float4* __restrict__ wp,
    ushort4* __restrict__ xb, ushort4* __restrict__ wqb, ushort4* __restrict__ wpb) {
  int i = blockIdx.x * 256 + threadIdx.x;
  const float4* src;
  ushort4* dst;
  if (i < XN4_) {
    src = x + i; dst = xb + i;
  } else if (i < XN4_ + WQ4_) {
    src = wq + (i - XN4_); dst = wqb + (i - XN4_);
  } else {
    src = wp + (i - XN4_ - WQ4_); dst = wpb + (i - XN4_ - WQ4_);
  }
  float4 v = *src;
  ushort4 o;
  o.x = f2bf(v.x); o.y = f2bf(v.y); o.z = f2bf(v.z); o.w = f2bf(v.w);
  *dst = o;
}

// ---------------- 128x128 bf16 GEMM mainloop, SWAPPED operands ----------------
__device__ __forceinline__ void gemm128_mainloop(
    const ushort* __restrict__ A, const ushort* __restrict__ Bw, int K,
    int bm, int bn, ushort* As, ushort* Bs, f32x4 acc[4][4]) {
  const int tid = threadIdx.x;
  const int lane = tid & 63;
  const int w = tid >> 6, wr = w >> 1, wc = w & 1;
  const int fr = lane & 15, fq = lane >> 4;
  const int srow = tid >> 3, scol = (tid & 7) * 8;

  const ushort* Ag = A + (size_t)(bm * 128 + srow) * K + scol;
  const ushort* Bg = Bw + (size_t)(bn * 128 + srow) * K + scol;
  ushort* Asd = As + tid * 8;
  ushort* Bsd = Bs + tid * 8;

  for (int kt = 0; kt < K; kt += 64) {
    __syncthreads();
#pragma unroll
    for (int c = 0; c < 4; ++c) {
      gload_lds16(Ag + (size_t)(c * 32) * K + kt, Asd + c * 2048);
      gload_lds16(Bg + (size_t)(c * 32) * K + kt, Bsd + c * 2048);
    }
    __syncthreads();

    short8 af[2][4], bf[2][4];
#pragma unroll
    for (int kk = 0; kk < 2; ++kk) {
#pragma unroll
      for (int mi = 0; mi < 4; ++mi)
        af[kk][mi] = *(const short8*)&As[(wr * 64 + mi * 16 + fr) * 64 + kk * 32 + fq * 8];
#pragma unroll
      for (int ni = 0; ni < 4; ++ni)
        bf[kk][ni] = *(const short8*)&Bs[(wc * 64 + ni * 16 + fr) * 64 + kk * 32 + fq * 8];
    }
#pragma unroll
    for (int kk = 0; kk < 2; ++kk)
#pragma unroll
      for (int mi = 0; mi < 4; ++mi)
#pragma unroll
        for (int ni = 0; ni < 4; ++ni)
          acc[mi][ni] = __builtin_amdgcn_mfma_f32_16x16x32_bf16(
              bf[kk][ni], af[kk][mi], acc[mi][ni], 0, 0, 0);  // swapped
  }
}

// ---------------- QKV GEMM: packed q/k epilogue; q pre-scaled; V^T ----------------
__global__ __launch_bounds__(256) void gemm_qkv_kernel(
    const ushort* __restrict__ xb, const ushort* __restrict__ wqkv,
    const float* __restrict__ bqkv,
    ushort* __restrict__ qo, ushort* __restrict__ ko, ushort* __restrict__ vo) {
  __shared__ ushort As[128 * 64];
  __shared__ ushort Bs[128 * 64];
  f32x4 acc[4][4] = {};
  const int bn = blockIdx.x, bm = blockIdx.y;
  gemm128_mainloop(xb, wqkv, DIM_, bm, bn, As, Bs, acc);

  const int tid = threadIdx.x, lane = tid & 63;
  const int w = tid >> 6, wr = w >> 1, wc = w & 1;
  const int fr = lane & 15, fq = lane >> 4;
#pragma unroll
  for (int mi = 0; mi < 4; ++mi) {
    int ng = bm * 128 + wr * 64 + mi * 16 + fr;  // token index [0,4096)
    int b = ng >> 11, n = ng & 2047;
#pragma unroll
    for (int ni = 0; ni < 4; ++ni) {
      int colb = bn * 128 + wc * 64 + ni * 16 + fq * 4;  // 4-aligned output col
      float4 b4 = *(const float4*)&bqkv[colb];
      int i3 = colb >> 10, h = (colb >> 6) & 15, hdq = colb & 63;
      float v0 = acc[mi][ni][0] + b4.x;
      float v1 = acc[mi][ni][1] + b4.y;
      float v2 = acc[mi][ni][2] + b4.z;
      float v3 = acc[mi][ni][3] + b4.w;
      if (i3 == 2) {
        // V^T [bh][d][N]
        size_t base = ((size_t)((b * H_ + h) * HD_ + hdq)) * N_ + n;
        vo[base]          = f2bf(v0);
        vo[base + N_]     = f2bf(v1);
        vo[base + 2 * N_] = f2bf(v2);
        vo[base + 3 * N_] = f2bf(v3);
      } else {
        // q is pre-scaled by 0.125*log2e so attn exp2 needs no multiply
        const float s = (i3 == 0) ? SBF_ : 1.0f;
        ushort* base = (i3 == 0) ? qo : ko;
        ushort4 o;
        o.x = f2bf(v0 * s); o.y = f2bf(v1 * s);
        o.z = f2bf(v2 * s); o.w = f2bf(v3 * s);
        *(ushort4*)&base[((size_t)(b * H_ + h) * N_ + n) * HD_ + hdq] = o;
      }
    }
  }
}

// ---------------- Proj GEMM: float4 output + bias ----------------
__global__ __launch_bounds__(256) void gemm_proj_kernel(
    const ushort* __restrict__ ao, const ushort* __restrict__ wp,
    const float* __restrict__ bp, float* __restrict__ out) {
  __shared__ ushort As[128 * 64];
  __shared__ ushort Bs[128 * 64];
  f32x4 acc[4][4] = {};
  const int bn = blockIdx.x, bm = blockIdx.y;
  gemm128_mainloop(ao, wp, DIM_, bm, bn, As, Bs, acc);

  const int tid = threadIdx.x, lane = tid & 63;
  const int w = tid >> 6, wr = w >> 1, wc = w & 1;
  const int fr = lane & 15, fq = lane >> 4;
#pragma unroll
  for (int mi = 0; mi < 4; ++mi) {
    int mg = bm * 128 + wr * 64 + mi * 16 + fr;
#pragma unroll
    for (int ni = 0; ni < 4; ++ni) {
      int colb = bn * 128 + wc * 64 + ni * 16 + fq * 4;
      float4 b4 = *(const float4*)&bp[colb];
      float4 o;
      o.x = acc[mi][ni][0] + b4.x;
      o.y = acc[mi][ni][1] + b4.y;
      o.z = acc[mi][ni][2] + b4.z;
      o.w = acc[mi][ni][3] + b4.w;
      *(float4*)&out[(size_t)mg * DIM_ + colb] = o;
    }
  }
}

// ---------------- Flash attention v8: v6 program, 2-wave blocks ----------------
// Same per-wave schedule as the verified v6 (32 q-rows/wave, full KV sweep,
// bias-in-C, static softmax, in-register P, 2-tile pipeline), but blocks are
// 2 waves / 64 q-rows -> grid 1024 and 5 blocks/CU (LDS 5x32KB = 160KB exactly)
// = 10 waves/CU of INDEPENDENT blocks for cross-pipe overlap (R11 was 2
// barrier-locked blocks/CU; pipes summed serially).
__global__ __launch_bounds__(128, 2) void attn_kernel(
    const ushort* __restrict__ Qg, const ushort* __restrict__ Kg,
    const ushort* __restrict__ Vtg, const float* __restrict__ rel,
    ushort* __restrict__ outb) {
  __shared__ ushort Ks[2][64 * 64];  // [key][d ^ ((key&7)<<3)]
  __shared__ ushort Vs[2][64 * 64];  // [d][key ^ ((d&7)<<3)]

  const int bid = blockIdx.x;                 // [0,1024)
  const int xcd = bid & 7, idx = bid >> 3;    // idx in [0,128)
  const int bh = xcd * 4 + (idx >> 5);        // 4 bh per XCD
  const int q0 = (idx & 31) * 64;             // 32 q-chunks of 64 rows
  const int h = bh & 15;
  const int tid = threadIdx.x, lane = tid & 63, w = tid >> 6;  // w in {0,1}
  const int ql = lane & 31, hi = lane >> 5;

  // bias (exp2-domain) in the MFMA C-operand: key%8 = (reg&3)+4*hi, q%8 = ql&7
  f32x16 biasC;
  {
    float b0 = rel[h * 64 + (ql & 7) * 8 + 0 + 4 * hi] * LOG2E_;
    float b1 = rel[h * 64 + (ql & 7) * 8 + 1 + 4 * hi] * LOG2E_;
    float b2 = rel[h * 64 + (ql & 7) * 8 + 2 + 4 * hi] * LOG2E_;
    float b3 = rel[h * 64 + (ql & 7) * 8 + 3 + 4 * hi] * LOG2E_;
#pragma unroll
    for (int z = 0; z < 16; z += 4) {
      biasC[z] = b0; biasC[z + 1] = b1; biasC[z + 2] = b2; biasC[z + 3] = b3;
    }
  }

  // Q B-fragments (q pre-scaled by 0.125*log2e at the producer)
  const ushort* qrow = Qg + ((size_t)bh * N_ + q0 + w * 32 + ql) * HD_;
  short8 qf[4];
#pragma unroll
  for (int kk = 0; kk < 4; ++kk)
    qf[kk] = *(const short8*)&qrow[kk * 16 + hi * 8];

  float l = 0.f;
  f32x16 oacc[2] = {};
  f32x16 sA[2], sB[2];

  // staging: 128 threads, 4 chunks of 16 rows each; pre-swizzled source col
  const int srow8 = tid >> 3;                    // row-in-chunk [0,16)
  const int swsrc = ((tid & 7) * 8) ^ ((srow8 & 7) << 3);
  int kcol[4];
#pragma unroll
  for (int kk = 0; kk < 4; ++kk)
    kcol[kk] = (kk * 16 + hi * 8) ^ ((ql & 7) << 3);

#define STAGE_K(t, bb)                                                              \
  {                                                                                 \
    const size_t kv0 = (size_t)(t) * 64;                                            \
    _Pragma("unroll") for (int c = 0; c < 4; ++c)                                   \
        gload_lds16(Kg + ((size_t)bh * N_ + kv0 + c * 16 + srow8) * HD_ + swsrc,    \
                    &Ks[bb][c * 1024 + tid * 8]);                                   \
  }
#define STAGE_V(t, bb)                                                              \
  {                                                                                 \
    const size_t kv0 = (size_t)(t) * 64;                                            \
    _Pragma("unroll") for (int c = 0; c < 4; ++c)                                   \
        gload_lds16(Vtg + ((size_t)(bh * HD_ + c * 16 + srow8)) * N_ + kv0 + swsrc, \
                    &Vs[bb][c * 1024 + tid * 8]);                                   \
  }

  // QK^T with C initialized to bias: exp2 applies directly to S
#define QKT(S, K_)                                                                  \
  {                                                                                 \
    S[0] = biasC;                                                                   \
    S[1] = biasC;                                                                   \
    __builtin_amdgcn_s_setprio(1);                                                  \
    _Pragma("unroll") for (int kk = 0; kk < 4; ++kk) {                              \
      short8 kf0 = *(const short8*)&(K_)[ql * 64 + kcol[kk]];                       \
      short8 kf1 = *(const short8*)&(K_)[(32 + ql) * 64 + kcol[kk]];                \
      S[0] = __builtin_amdgcn_mfma_f32_32x32x16_bf16(kf0, qf[kk], S[0], 0, 0, 0);   \
      S[1] = __builtin_amdgcn_mfma_f32_32x32x16_bf16(kf1, qf[kk], S[1], 0, 0, 0);   \
    }                                                                               \
    __builtin_amdgcn_s_setprio(0);                                                  \
  }

  // softmax + in-register P exchange + PV (rs reduce via shfl_xor: R5 lesson --
  // never feed two copies of one value into a two-operand "+v" asm swap)
#define SOFTPV(S, V_)                                                               \
  {                                                                                 \
    float rs_[4] = {0.f, 0.f, 0.f, 0.f};                                            \
    uint32_t c[2][8];                                                               \
    _Pragma("unroll") for (int blk = 0; blk < 2; ++blk) {                           \
      _Pragma("unroll") for (int i = 0; i < 8; ++i) {                               \
        float pa = __builtin_amdgcn_exp2f(S[blk][2 * i]);                           \
        float pb = __builtin_amdgcn_exp2f(S[blk][2 * i + 1]);                       \
        rs_[i & 3] += pa + pb;                                                      \
        c[blk][i] = ((uint32_t)f2bf(pb) << 16) | f2bf(pa);                          \
      }                                                                             \
    }                                                                               \
    float rs = (rs_[0] + rs_[1]) + (rs_[2] + rs_[3]);                               \
    rs += __shfl_xor(rs, 32, 64);                                                   \
    l += rs;                                                                        \
    _Pragma("unroll") for (int blk = 0; blk < 2; ++blk) {                           \
      asm("v_permlane32_swap_b32 %0, %1" : "+v"(c[blk][0]), "+v"(c[blk][2]));       \
      asm("v_permlane32_swap_b32 %0, %1" : "+v"(c[blk][1]), "+v"(c[blk][3]));       \
      asm("v_permlane32_swap_b32 %0, %1" : "+v"(c[blk][4]), "+v"(c[blk][6]));       \
      asm("v_permlane32_swap_b32 %0, %1" : "+v"(c[blk][5]), "+v"(c[blk][7]));       \
    }                                                                               \
    __builtin_amdgcn_s_setprio(1);                                                  \
    _Pragma("unroll") for (int kk = 0; kk < 4; ++kk) {                              \
      union { uint32_t u[4]; short8 s8; } pb_;                                      \
      pb_.u[0] = c[kk >> 1][(kk & 1) * 4 + 0];                                      \
      pb_.u[1] = c[kk >> 1][(kk & 1) * 4 + 1];                                      \
      pb_.u[2] = c[kk >> 1][(kk & 1) * 4 + 2];                                      \
      pb_.u[3] = c[kk >> 1][(kk & 1) * 4 + 3];                                      \
      _Pragma("unroll") for (int db = 0; db < 2; ++db) {                            \
        short8 vf = *(const short8*)&(V_)[(db * 32 + ql) * 64 + kcol[kk]];          \
        oacc[db] = __builtin_amdgcn_mfma_f32_32x32x16_bf16(vf, pb_.s8, oacc[db], 0, 0, 0); \
      }                                                                             \
    }                                                                               \
    __builtin_amdgcn_s_setprio(0);                                                  \
  }

  // prologue
  STAGE_K(0, 0);
  STAGE_V(0, 0);
  __syncthreads();
  QKT(sA, Ks[0]);
  STAGE_K(1, 1);
  __syncthreads();

#pragma unroll 1
  for (int tt = 0; tt < 15; ++tt) {
    const int t = 2 * tt;
    STAGE_K(t + 2, 0);
    STAGE_V(t + 1, 1);
    QKT(sB, Ks[1]);
    SOFTPV(sA, Vs[0]);
    __syncthreads();
    STAGE_K(t + 3, 1);
    STAGE_V(t + 2, 0);
    QKT(sA, Ks[0]);
    SOFTPV(sB, Vs[1]);
    __syncthreads();
  }
  STAGE_V(31, 1);
  QKT(sB, Ks[1]);
  SOFTPV(sA, Vs[0]);
  __syncthreads();
  SOFTPV(sB, Vs[1]);

  // epilogue: O^T[d][q] -> out[b][q][h*64+d]
  const int b = bh >> 4;
  const float invl = 1.0f / l;
  const size_t rowbase = ((size_t)(b * N_ + q0 + w * 32 + ql)) * DIM_ + h * HD_;
#pragma unroll
  for (int db = 0; db < 2; ++db)
#pragma unroll
    for (int g = 0; g < 4; ++g) {
      ushort4 o;
      o.x = f2bf(oacc[db][4 * g + 0] * invl);
      o.y = f2bf(oacc[db][4 * g + 1] * invl);
      o.z = f2bf(oacc[db][4 * g + 2] * invl);
      o.w = f2bf(oacc[db][4 * g + 3] * invl);
      *(ushort4*)&outb[rowbase + db * 32 + 8 * g + 4 * hi] = o;
    }
#undef STAGE_K
#undef STAGE_V
#undef QKT
#undef SOFTPV
}

// ---------------- host launcher ----------------
extern "C" void kernel_launch(void* const* d_in, const int* in_sizes, int n_in,
                              void* d_out, int out_size, void* d_ws, size_t ws_size,
                              hipStream_t stream) {
  const float* x      = (const float*)d_in[0];
  const float* w_qkv  = (const float*)d_in[1];
  const float* b_qkv  = (const float*)d_in[2];
  const float* w_proj = (const float*)d_in[3];
  const float* b_proj = (const float*)d_in[4];
  const float* rel    = (const float*)d_in[5];

  char* ws = (char*)d_ws;
  ushort* xb     = (ushort*)(ws + 0);
  ushort* wqkvb  = (ushort*)(ws + 8388608);
  ushort* wprojb = (ushort*)(ws + 14680064);
  ushort* qb     = (ushort*)(ws + 16777216);
  ushort* kb     = (ushort*)(ws + 25165824);
  ushort* vb     = (ushort*)(ws + 33554432);   // V^T [32][64][2048]
  ushort* aob    = (ushort*)(ws + 41943040);
  (void)in_sizes; (void)n_in; (void)out_size; (void)ws_size;

  cvt_all_kernel<<<8192, 256, 0, stream>>>(
      (const float4*)x, (const float4*)w_qkv, (const float4*)w_proj,
      (ushort4*)xb, (ushort4*)wqkvb, (ushort4*)wprojb);

  gemm_qkv_kernel<<<dim3(24, 32), 256, 0, stream>>>(xb, wqkvb, b_qkv, qb, kb, vb);
  attn_kernel<<<1024, 128, 0, stream>>>(qb, kb, vb, rel, aob);
  gemm_proj_kernel<<<dim3(8, 32), 256, 0, stream>>>(aob, wprojb, b_proj, (float*)d_out);
}

// Round 14
// 136.285 us; speedup vs baseline: 1.1882x; 1.0219x over previous
//
#include <hip/hip_runtime.h>
#include <hip/hip_bf16.h>
#include <stdint.h>

// Problem constants
#define B_ 2
#define N_ 2048
#define DIM_ 1024
#define H_ 16
#define HD_ 64
#define NT_ 32  // N_/64 kv tiles

typedef __attribute__((ext_vector_type(8))) short short8;
typedef __attribute__((ext_vector_type(4))) float f32x4;
typedef __attribute__((ext_vector_type(16))) float f32x16;

#define LOG2E_ 1.4426950408889634f
#define SBF_ (0.125f * LOG2E_)

__device__ __forceinline__ unsigned short f2bf(float f) {
  __bf16 h = (__bf16)f;
  return __builtin_bit_cast(unsigned short, h);
}

__device__ __forceinline__ void gload_lds16(const void* g, void* l) {
  __builtin_amdgcn_global_load_lds(
      (const __attribute__((address_space(1))) unsigned int*)g,
      (__attribute__((address_space(3))) unsigned int*)l,
      16, 0, 0);
}

// ---------------- merged f32 -> bf16 conversion ----------------
#define XN4_ 1048576   // (2*2048*1024)/4
#define WQ4_ 786432    // (3*1024*1024)/4
__global__ __launch_bounds__(256) void cvt_all_kernel(
    const float4* __restrict__ x, const float4* __restrict__ wq,
    const float4* __restrict__ wp,
    ushort4* __restrict__ xb, ushort4* __restrict__ wqb, ushort4* __restrict__ wpb) {
  int i = blockIdx.x * 256 + threadIdx.x;
  const float4* src;
  ushort4* dst;
  if (i < XN4_) {
    src = x + i; dst = xb + i;
  } else if (i < XN4_ + WQ4_) {
    src = wq + (i - XN4_); dst = wqb + (i - XN4_);
  } else {
    src = wp + (i - XN4_ - WQ4_); dst = wpb + (i - XN4_ - WQ4_);
  }
  float4 v = *src;
  ushort4 o;
  o.x = f2bf(v.x); o.y = f2bf(v.y); o.z = f2bf(v.z); o.w = f2bf(v.w);
  *dst = o;
}

// ---------------- 128x128 bf16 GEMM mainloop, SWAPPED operands ----------------
__device__ __forceinline__ void gemm128_mainloop(
    const ushort* __restrict__ A, const ushort* __restrict__ Bw, int K,
    int bm, int bn, ushort* As, ushort* Bs, f32x4 acc[4][4]) {
  const int tid = threadIdx.x;
  const int lane = tid & 63;
  const int w = tid >> 6, wr = w >> 1, wc = w & 1;
  const int fr = lane & 15, fq = lane >> 4;
  const int srow = tid >> 3, scol = (tid & 7) * 8;

  const ushort* Ag = A + (size_t)(bm * 128 + srow) * K + scol;
  const ushort* Bg = Bw + (size_t)(bn * 128 + srow) * K + scol;
  ushort* Asd = As + tid * 8;
  ushort* Bsd = Bs + tid * 8;

  for (int kt = 0; kt < K; kt += 64) {
    __syncthreads();
#pragma unroll
    for (int c = 0; c < 4; ++c) {
      gload_lds16(Ag + (size_t)(c * 32) * K + kt, Asd + c * 2048);
      gload_lds16(Bg + (size_t)(c * 32) * K + kt, Bsd + c * 2048);
    }
    __syncthreads();

    short8 af[2][4], bf[2][4];
#pragma unroll
    for (int kk = 0; kk < 2; ++kk) {
#pragma unroll
      for (int mi = 0; mi < 4; ++mi)
        af[kk][mi] = *(const short8*)&As[(wr * 64 + mi * 16 + fr) * 64 + kk * 32 + fq * 8];
#pragma unroll
      for (int ni = 0; ni < 4; ++ni)
        bf[kk][ni] = *(const short8*)&Bs[(wc * 64 + ni * 16 + fr) * 64 + kk * 32 + fq * 8];
    }
#pragma unroll
    for (int kk = 0; kk < 2; ++kk)
#pragma unroll
      for (int mi = 0; mi < 4; ++mi)
#pragma unroll
        for (int ni = 0; ni < 4; ++ni)
          acc[mi][ni] = __builtin_amdgcn_mfma_f32_16x16x32_bf16(
              bf[kk][ni], af[kk][mi], acc[mi][ni], 0, 0, 0);  // swapped
  }
}

// ---------------- QKV GEMM: packed q/k epilogue; q pre-scaled; V^T ----------------
// 1D grid 768, bijective XCD swizzle: each XCD owns 4 contiguous bm panels (T1).
__global__ __launch_bounds__(256) void gemm_qkv_kernel(
    const ushort* __restrict__ xb, const ushort* __restrict__ wqkv,
    const float* __restrict__ bqkv,
    ushort* __restrict__ qo, ushort* __restrict__ ko, ushort* __restrict__ vo) {
  __shared__ ushort As[128 * 64];
  __shared__ ushort Bs[128 * 64];
  f32x4 acc[4][4] = {};
  const int bid = blockIdx.x;               // [0,768), 768 % 8 == 0
  const int virt = (bid & 7) * 96 + (bid >> 3);
  const int bm = virt / 24, bn = virt % 24;
  gemm128_mainloop(xb, wqkv, DIM_, bm, bn, As, Bs, acc);

  const int tid = threadIdx.x, lane = tid & 63;
  const int w = tid >> 6, wr = w >> 1, wc = w & 1;
  const int fr = lane & 15, fq = lane >> 4;
#pragma unroll
  for (int mi = 0; mi < 4; ++mi) {
    int ng = bm * 128 + wr * 64 + mi * 16 + fr;  // token index [0,4096)
    int b = ng >> 11, n = ng & 2047;
#pragma unroll
    for (int ni = 0; ni < 4; ++ni) {
      int colb = bn * 128 + wc * 64 + ni * 16 + fq * 4;  // 4-aligned output col
      float4 b4 = *(const float4*)&bqkv[colb];
      int i3 = colb >> 10, h = (colb >> 6) & 15, hdq = colb & 63;
      float v0 = acc[mi][ni][0] + b4.x;
      float v1 = acc[mi][ni][1] + b4.y;
      float v2 = acc[mi][ni][2] + b4.z;
      float v3 = acc[mi][ni][3] + b4.w;
      if (i3 == 2) {
        // V^T [bh][d][N]
        size_t base = ((size_t)((b * H_ + h) * HD_ + hdq)) * N_ + n;
        vo[base]          = f2bf(v0);
        vo[base + N_]     = f2bf(v1);
        vo[base + 2 * N_] = f2bf(v2);
        vo[base + 3 * N_] = f2bf(v3);
      } else {
        // q is pre-scaled by 0.125*log2e so attn exp2 needs no multiply
        const float s = (i3 == 0) ? SBF_ : 1.0f;
        ushort* base = (i3 == 0) ? qo : ko;
        ushort4 o;
        o.x = f2bf(v0 * s); o.y = f2bf(v1 * s);
        o.z = f2bf(v2 * s); o.w = f2bf(v3 * s);
        *(ushort4*)&base[((size_t)(b * H_ + h) * N_ + n) * HD_ + hdq] = o;
      }
    }
  }
}

// ---------------- Proj GEMM: float4 output + bias; XCD swizzle ----------------
__global__ __launch_bounds__(256) void gemm_proj_kernel(
    const ushort* __restrict__ ao, const ushort* __restrict__ wp,
    const float* __restrict__ bp, float* __restrict__ out) {
  __shared__ ushort As[128 * 64];
  __shared__ ushort Bs[128 * 64];
  f32x4 acc[4][4] = {};
  const int bid = blockIdx.x;               // [0,256), 256 % 8 == 0
  const int virt = (bid & 7) * 32 + (bid >> 3);
  const int bm = virt >> 3, bn = virt & 7;
  gemm128_mainloop(ao, wp, DIM_, bm, bn, As, Bs, acc);

  const int tid = threadIdx.x, lane = tid & 63;
  const int w = tid >> 6, wr = w >> 1, wc = w & 1;
  const int fr = lane & 15, fq = lane >> 4;
#pragma unroll
  for (int mi = 0; mi < 4; ++mi) {
    int mg = bm * 128 + wr * 64 + mi * 16 + fr;
#pragma unroll
    for (int ni = 0; ni < 4; ++ni) {
      int colb = bn * 128 + wc * 64 + ni * 16 + fq * 4;
      float4 b4 = *(const float4*)&bp[colb];
      float4 o;
      o.x = acc[mi][ni][0] + b4.x;
      o.y = acc[mi][ni][1] + b4.y;
      o.z = acc[mi][ni][2] + b4.z;
      o.w = acc[mi][ni][3] + b4.w;
      *(float4*)&out[(size_t)mg * DIM_ + colb] = o;
    }
  }
}

// ---------------- Flash attention v9: R11 program, 2 tiles per barrier ----------
// 4 waves x 32 q-rows, 512 blocks (grid-limited 2 blocks/CU). 4 LDS buffers
// (buf = tile & 3, 64KB): each interval stages a PAIR issue-first, computes the
// pair staged last interval {QKT,QKT,SOFTPV,SOFTPV}, one barrier -> 16 barriers
// instead of 32, and the 16-MFMA QKT burst gives the in-order wave a longer
// window to overlap softmax VALU with in-flight MFMAs.
__global__ __launch_bounds__(256, 2) void attn_kernel(
    const ushort* __restrict__ Qg, const ushort* __restrict__ Kg,
    const ushort* __restrict__ Vtg, const float* __restrict__ rel,
    ushort* __restrict__ outb) {
  __shared__ ushort Ks[4][4096];  // [key][d ^ ((key&7)<<3)]
  __shared__ ushort Vs[4][4096];  // [d][key ^ ((d&7)<<3)]

  const int bid = blockIdx.x;                 // [0,512)
  const int xcd = bid & 7, idx = bid >> 3;
  const int bh = xcd * 4 + (idx >> 4);
  const int q0 = (idx & 15) * 128;
  const int h = bh & 15;
  const int tid = threadIdx.x, lane = tid & 63, w = tid >> 6;
  const int ql = lane & 31, hi = lane >> 5;

  // bias (exp2-domain) in the MFMA C-operand: key%8 = (reg&3)+4*hi, q%8 = ql&7
  f32x16 biasC;
  {
    float b0 = rel[h * 64 + (ql & 7) * 8 + 0 + 4 * hi] * LOG2E_;
    float b1 = rel[h * 64 + (ql & 7) * 8 + 1 + 4 * hi] * LOG2E_;
    float b2 = rel[h * 64 + (ql & 7) * 8 + 2 + 4 * hi] * LOG2E_;
    float b3 = rel[h * 64 + (ql & 7) * 8 + 3 + 4 * hi] * LOG2E_;
#pragma unroll
    for (int z = 0; z < 16; z += 4) {
      biasC[z] = b0; biasC[z + 1] = b1; biasC[z + 2] = b2; biasC[z + 3] = b3;
    }
  }

  // Q B-fragments (q pre-scaled by 0.125*log2e at the producer)
  const ushort* qrow = Qg + ((size_t)bh * N_ + q0 + w * 32 + ql) * HD_;
  short8 qf[4];
#pragma unroll
  for (int kk = 0; kk < 4; ++kk)
    qf[kk] = *(const short8*)&qrow[kk * 16 + hi * 8];

  float l = 0.f;
  f32x16 oacc[2] = {};
  f32x16 sA[2], sB[2];

  const int srow = tid >> 3, scol = (tid & 7) * 8;
  const int swsrc = scol ^ ((srow & 7) << 3);
  int kcol[4];
#pragma unroll
  for (int kk = 0; kk < 4; ++kk)
    kcol[kk] = (kk * 16 + hi * 8) ^ ((ql & 7) << 3);

#define STAGE_K(t, bb)                                                              \
  {                                                                                 \
    const size_t kv0 = (size_t)(t) * 64;                                            \
    _Pragma("unroll") for (int c = 0; c < 2; ++c)                                   \
        gload_lds16(Kg + ((size_t)bh * N_ + kv0 + c * 32 + srow) * HD_ + swsrc,     \
                    &Ks[bb][c * 2048 + tid * 8]);                                   \
  }
#define STAGE_V(t, bb)                                                              \
  {                                                                                 \
    const size_t kv0 = (size_t)(t) * 64;                                            \
    _Pragma("unroll") for (int c = 0; c < 2; ++c)                                   \
        gload_lds16(Vtg + ((size_t)(bh * HD_ + c * 32 + srow)) * N_ + kv0 + swsrc,  \
                    &Vs[bb][c * 2048 + tid * 8]);                                   \
  }

  // QK^T with C initialized to bias: exp2 applies directly to S
#define QKT(S, K_)                                                                  \
  {                                                                                 \
    S[0] = biasC;                                                                   \
    S[1] = biasC;                                                                   \
    __builtin_amdgcn_s_setprio(1);                                                  \
    _Pragma("unroll") for (int kk = 0; kk < 4; ++kk) {                              \
      short8 kf0 = *(const short8*)&(K_)[ql * 64 + kcol[kk]];                       \
      short8 kf1 = *(const short8*)&(K_)[(32 + ql) * 64 + kcol[kk]];                \
      S[0] = __builtin_amdgcn_mfma_f32_32x32x16_bf16(kf0, qf[kk], S[0], 0, 0, 0);   \
      S[1] = __builtin_amdgcn_mfma_f32_32x32x16_bf16(kf1, qf[kk], S[1], 0, 0, 0);   \
    }                                                                               \
    __builtin_amdgcn_s_setprio(0);                                                  \
  }

  // softmax + in-register P exchange + PV (rs reduce via shfl_xor: R5 lesson --
  // never feed two copies of one value into a two-operand "+v" asm swap)
#define SOFTPV(S, V_)                                                               \
  {                                                                                 \
    float rs_[4] = {0.f, 0.f, 0.f, 0.f};                                            \
    uint32_t c[2][8];                                                               \
    _Pragma("unroll") for (int blk = 0; blk < 2; ++blk) {                           \
      _Pragma("unroll") for (int i = 0; i < 8; ++i) {                               \
        float pa = __builtin_amdgcn_exp2f(S[blk][2 * i]);                           \
        float pb = __builtin_amdgcn_exp2f(S[blk][2 * i + 1]);                       \
        rs_[i & 3] += pa + pb;                                                      \
        c[blk][i] = ((uint32_t)f2bf(pb) << 16) | f2bf(pa);                          \
      }                                                                             \
    }                                                                               \
    float rs = (rs_[0] + rs_[1]) + (rs_[2] + rs_[3]);                               \
    rs += __shfl_xor(rs, 32, 64);                                                   \
    l += rs;                                                                        \
    _Pragma("unroll") for (int blk = 0; blk < 2; ++blk) {                           \
      asm("v_permlane32_swap_b32 %0, %1" : "+v"(c[blk][0]), "+v"(c[blk][2]));       \
      asm("v_permlane32_swap_b32 %0, %1" : "+v"(c[blk][1]), "+v"(c[blk][3]));       \
      asm("v_permlane32_swap_b32 %0, %1" : "+v"(c[blk][4]), "+v"(c[blk][6]));       \
      asm("v_permlane32_swap_b32 %0, %1" : "+v"(c[blk][5]), "+v"(c[blk][7]));       \
    }                                                                               \
    __builtin_amdgcn_s_setprio(1);                                                  \
    _Pragma("unroll") for (int kk = 0; kk < 4; ++kk) {                              \
      union { uint32_t u[4]; short8 s8; } pb_;                                      \
      pb_.u[0] = c[kk >> 1][(kk & 1) * 4 + 0];                                      \
      pb_.u[1] = c[kk >> 1][(kk & 1) * 4 + 1];                                      \
      pb_.u[2] = c[kk >> 1][(kk & 1) * 4 + 2];                                      \
      pb_.u[3] = c[kk >> 1][(kk & 1) * 4 + 3];                                      \
      _Pragma("unroll") for (int db = 0; db < 2; ++db) {                            \
        short8 vf = *(const short8*)&(V_)[(db * 32 + ql) * 64 + kcol[kk]];          \
        oacc[db] = __builtin_amdgcn_mfma_f32_32x32x16_bf16(vf, pb_.s8, oacc[db], 0, 0, 0); \
      }                                                                             \
    }                                                                               \
    __builtin_amdgcn_s_setprio(0);                                                  \
  }

  // prologue: tiles 0,1 into bufs 0,1
  STAGE_K(0, 0); STAGE_V(0, 0);
  STAGE_K(1, 1); STAGE_V(1, 1);
  __syncthreads();

#pragma unroll 1
  for (int tt = 0; tt < 8; ++tt) {
    const int t0 = 4 * tt;
    // interval A: stage tiles t0+2,t0+3 -> bufs 2,3; compute t0,t0+1 from bufs 0,1
    STAGE_K(t0 + 2, 2); STAGE_V(t0 + 2, 2);
    STAGE_K(t0 + 3, 3); STAGE_V(t0 + 3, 3);
    QKT(sA, Ks[0]);
    QKT(sB, Ks[1]);
    SOFTPV(sA, Vs[0]);
    SOFTPV(sB, Vs[1]);
    __syncthreads();
    // interval B: stage tiles t0+4,t0+5 -> bufs 0,1; compute t0+2,t0+3 from bufs 2,3
    if (tt < 7) {
      STAGE_K(t0 + 4, 0); STAGE_V(t0 + 4, 0);
      STAGE_K(t0 + 5, 1); STAGE_V(t0 + 5, 1);
    }
    QKT(sA, Ks[2]);
    QKT(sB, Ks[3]);
    SOFTPV(sA, Vs[2]);
    SOFTPV(sB, Vs[3]);
    __syncthreads();
  }

  // epilogue: O^T[d][q] -> out[b][q][h*64+d]
  const int b = bh >> 4;
  const float invl = 1.0f / l;
  const size_t rowbase = ((size_t)(b * N_ + q0 + w * 32 + ql)) * DIM_ + h * HD_;
#pragma unroll
  for (int db = 0; db < 2; ++db)
#pragma unroll
    for (int g = 0; g < 4; ++g) {
      ushort4 o;
      o.x = f2bf(oacc[db][4 * g + 0] * invl);
      o.y = f2bf(oacc[db][4 * g + 1] * invl);
      o.z = f2bf(oacc[db][4 * g + 2] * invl);
      o.w = f2bf(oacc[db][4 * g + 3] * invl);
      *(ushort4*)&outb[rowbase + db * 32 + 8 * g + 4 * hi] = o;
    }
#undef STAGE_K
#undef STAGE_V
#undef QKT
#undef SOFTPV
}

// ---------------- host launcher ----------------
extern "C" void kernel_launch(void* const* d_in, const int* in_sizes, int n_in,
                              void* d_out, int out_size, void* d_ws, size_t ws_size,
                              hipStream_t stream) {
  const float* x      = (const float*)d_in[0];
  const float* w_qkv  = (const float*)d_in[1];
  const float* b_qkv  = (const float*)d_in[2];
  const float* w_proj = (const float*)d_in[3];
  const float* b_proj = (const float*)d_in[4];
  const float* rel    = (const float*)d_in[5];

  char* ws = (char*)d_ws;
  ushort* xb     = (ushort*)(ws + 0);
  ushort* wqkvb  = (ushort*)(ws + 8388608);
  ushort* wprojb = (ushort*)(ws + 14680064);
  ushort* qb     = (ushort*)(ws + 16777216);
  ushort* kb     = (ushort*)(ws + 25165824);
  ushort* vb     = (ushort*)(ws + 33554432);   // V^T [32][64][2048]
  ushort* aob    = (ushort*)(ws + 41943040);
  (void)in_sizes; (void)n_in; (void)out_size; (void)ws_size;

  cvt_all_kernel<<<8192, 256, 0, stream>>>(
      (const float4*)x, (const float4*)w_qkv, (const float4*)w_proj,
      (ushort4*)xb, (ushort4*)wqkvb, (ushort4*)wprojb);

  gemm_qkv_kernel<<<768, 256, 0, stream>>>(xb, wqkvb, b_qkv, qb, kb, vb);
  attn_kernel<<<512, 256, 0, stream>>>(qb, kb, vb, rel, aob);
  gemm_proj_kernel<<<256, 256, 0, stream>>>(aob, wprojb, b_proj, (float*)d_out);
}

// Round 16
// 130.832 us; speedup vs baseline: 1.2377x; 1.0417x over previous
//
#include <hip/hip_runtime.h>
#include <hip/hip_bf16.h>
#include <stdint.h>

// Problem constants
#define B_ 2
#define N_ 2048
#define DIM_ 1024
#define H_ 16
#define HD_ 64
#define NT_ 32  // N_/64 kv tiles

typedef __attribute__((ext_vector_type(8))) short short8;
typedef __attribute__((ext_vector_type(4))) float f32x4;
typedef __attribute__((ext_vector_type(16))) float f32x16;

#define LOG2E_ 1.4426950408889634f
#define SBF_ (0.125f * LOG2E_)

__device__ __forceinline__ unsigned short f2bf(float f) {
  __bf16 h = (__bf16)f;
  return __builtin_bit_cast(unsigned short, h);
}

__device__ __forceinline__ void gload_lds16(const void* g, void* l) {
  __builtin_amdgcn_global_load_lds(
      (const __attribute__((address_space(1))) unsigned int*)g,
      (__attribute__((address_space(3))) unsigned int*)l,
      16, 0, 0);
}

// ---------------- merged f32 -> bf16 conversion ----------------
#define XN4_ 1048576   // (2*2048*1024)/4
#define WQ4_ 786432    // (3*1024*1024)/4
__global__ __launch_bounds__(256) void cvt_all_kernel(
    const float4* __restrict__ x, const float4* __restrict__ wq,
    const float4* __restrict__ wp,
    ushort4* __restrict__ xb, ushort4* __restrict__ wqb, ushort4* __restrict__ wpb) {
  int i = blockIdx.x * 256 + threadIdx.x;
  const float4* src;
  ushort4* dst;
  if (i < XN4_) {
    src = x + i; dst = xb + i;
  } else if (i < XN4_ + WQ4_) {
    src = wq + (i - XN4_); dst = wqb + (i - XN4_);
  } else {
    src = wp + (i - XN4_ - WQ4_); dst = wpb + (i - XN4_ - WQ4_);
  }
  float4 v = *src;
  ushort4 o;
  o.x = f2bf(v.x); o.y = f2bf(v.y); o.z = f2bf(v.z); o.w = f2bf(v.w);
  *dst = o;
}

// ---------------- 128x128 bf16 GEMM mainloop, SWAPPED operands ----------------
// acc = (A_tile @ B_tile^T)^T via mfma(bf, af): c_col (lane&15) = A-row m,
// c_row (fq*4+r) = B-row col -> thread holds 4 CONSECUTIVE output columns.
__device__ __forceinline__ void gemm128_mainloop(
    const ushort* __restrict__ A, const ushort* __restrict__ Bw, int K,
    int bm, int bn, ushort* As, ushort* Bs, f32x4 acc[4][4]) {
  const int tid = threadIdx.x;
  const int lane = tid & 63;
  const int w = tid >> 6, wr = w >> 1, wc = w & 1;
  const int fr = lane & 15, fq = lane >> 4;
  const int srow = tid >> 3, scol = (tid & 7) * 8;

  const ushort* Ag = A + (size_t)(bm * 128 + srow) * K + scol;
  const ushort* Bg = Bw + (size_t)(bn * 128 + srow) * K + scol;
  ushort* Asd = As + tid * 8;
  ushort* Bsd = Bs + tid * 8;

  for (int kt = 0; kt < K; kt += 64) {
    __syncthreads();
#pragma unroll
    for (int c = 0; c < 4; ++c) {
      gload_lds16(Ag + (size_t)(c * 32) * K + kt, Asd + c * 2048);
      gload_lds16(Bg + (size_t)(c * 32) * K + kt, Bsd + c * 2048);
    }
    __syncthreads();

    short8 af[2][4], bf[2][4];
#pragma unroll
    for (int kk = 0; kk < 2; ++kk) {
#pragma unroll
      for (int mi = 0; mi < 4; ++mi)
        af[kk][mi] = *(const short8*)&As[(wr * 64 + mi * 16 + fr) * 64 + kk * 32 + fq * 8];
#pragma unroll
      for (int ni = 0; ni < 4; ++ni)
        bf[kk][ni] = *(const short8*)&Bs[(wc * 64 + ni * 16 + fr) * 64 + kk * 32 + fq * 8];
    }
#pragma unroll
    for (int kk = 0; kk < 2; ++kk)
#pragma unroll
      for (int mi = 0; mi < 4; ++mi)
#pragma unroll
        for (int ni = 0; ni < 4; ++ni)
          acc[mi][ni] = __builtin_amdgcn_mfma_f32_16x16x32_bf16(
              bf[kk][ni], af[kk][mi], acc[mi][ni], 0, 0, 0);  // swapped
  }
}

// ---------------- QKV GEMM ----------------
// grid dim3(24,32) (NO XCD swizzle: R14 showed per-XCD working set 7MB > 4MB L2).
// q/k: packed ushort4 rows, q pre-scaled. V blocks (bn>=16, block-uniform):
// in-LDS 128x128 transpose -> V^T stores become fully-coalesced 16B writes.
// R15 bug fixed: read-back covers all 128 tokens x 128 rows
// (row = pass*16 + tid>>4, tok0 = (tid&15)*8; old tid>>3/(tid&7)*8 left
// tokens 64..127 unwritten -> uninitialized V^T -> inf).
__global__ __launch_bounds__(256) void gemm_qkv_kernel(
    const ushort* __restrict__ xb, const ushort* __restrict__ wqkv,
    const float* __restrict__ bqkv,
    ushort* __restrict__ qo, ushort* __restrict__ ko, ushort* __restrict__ vo) {
  __shared__ ushort smem[128 * 128];  // mainloop: As/Bs; V-epilogue: 128x128 transpose
  ushort* As = smem;
  ushort* Bs = smem + 128 * 64;
  f32x4 acc[4][4] = {};
  const int bn = blockIdx.x, bm = blockIdx.y;
  gemm128_mainloop(xb, wqkv, DIM_, bm, bn, As, Bs, acc);

  const int tid = threadIdx.x, lane = tid & 63;
  const int w = tid >> 6, wr = w >> 1, wc = w & 1;
  const int fr = lane & 15, fq = lane >> 4;
  const int b = (bm * 128) >> 11;  // batch constant per block (128 | 2048)

  if (bn >= 16) {
    // ---- V block: transpose through LDS, coalesced V^T stores ----
    __syncthreads();  // all waves done reading As/Bs
#pragma unroll
    for (int mi = 0; mi < 4; ++mi) {
      int tok = wr * 64 + mi * 16 + fr;  // token within 128-row tile
#pragma unroll
      for (int ni = 0; ni < 4; ++ni) {
        int row0 = wc * 64 + ni * 16 + fq * 4;           // d within 128-col tile
        float4 b4 = *(const float4*)&bqkv[bn * 128 + row0];
        float vv[4] = {acc[mi][ni][0] + b4.x, acc[mi][ni][1] + b4.y,
                       acc[mi][ni][2] + b4.z, acc[mi][ni][3] + b4.w};
#pragma unroll
        for (int r = 0; r < 4; ++r) {
          int row = row0 + r;
          smem[row * 128 + (tok ^ ((row & 7) << 3))] = f2bf(vv[r]);
        }
      }
    }
    __syncthreads();
    // read back 8 consecutive tokens per b128 (conflict-free via XOR), store coalesced
    const int n0 = bm * 128;
#pragma unroll
    for (int pass = 0; pass < 8; ++pass) {
      int row = pass * 16 + (tid >> 4);       // 16 rows/pass x 8 passes = 128 rows
      int tok0 = (tid & 15) * 8;              // 16 lanes x 8 = 128 tokens
      short8 v = *(const short8*)&smem[row * 128 + (tok0 ^ ((row & 7) << 3))];
      int col = bn * 128 + row;               // global col in [2048,3072)
      int h = (col >> 6) & 15, hd = col & 63;
      *(short8*)&vo[((size_t)((b * H_ + h) * HD_ + hd)) * N_ + (n0 & 2047) + tok0] = v;
    }
  } else {
    // ---- q/k block: packed ushort4 rows ----
#pragma unroll
    for (int mi = 0; mi < 4; ++mi) {
      int ng = bm * 128 + wr * 64 + mi * 16 + fr;  // token index [0,4096)
      int n = ng & 2047;
#pragma unroll
      for (int ni = 0; ni < 4; ++ni) {
        int colb = bn * 128 + wc * 64 + ni * 16 + fq * 4;
        float4 b4 = *(const float4*)&bqkv[colb];
        int i3 = colb >> 10, h = (colb >> 6) & 15, hdq = colb & 63;
        const float s = (i3 == 0) ? SBF_ : 1.0f;  // q pre-scaled by 0.125*log2e
        ushort* base = (i3 == 0) ? qo : ko;
        ushort4 o;
        o.x = f2bf((acc[mi][ni][0] + b4.x) * s);
        o.y = f2bf((acc[mi][ni][1] + b4.y) * s);
        o.z = f2bf((acc[mi][ni][2] + b4.z) * s);
        o.w = f2bf((acc[mi][ni][3] + b4.w) * s);
        *(ushort4*)&base[((size_t)((ng >> 11) * H_ + h) * N_ + n) * HD_ + hdq] = o;
      }
    }
  }
}

// ---------------- Proj GEMM: float4 output + bias; XCD swizzle (neutral, kept) ----
__global__ __launch_bounds__(256) void gemm_proj_kernel(
    const ushort* __restrict__ ao, const ushort* __restrict__ wp,
    const float* __restrict__ bp, float* __restrict__ out) {
  __shared__ ushort As[128 * 64];
  __shared__ ushort Bs[128 * 64];
  f32x4 acc[4][4] = {};
  const int bid = blockIdx.x;               // [0,256), 256 % 8 == 0
  const int virt = (bid & 7) * 32 + (bid >> 3);
  const int bm = virt >> 3, bn = virt & 7;
  gemm128_mainloop(ao, wp, DIM_, bm, bn, As, Bs, acc);

  const int tid = threadIdx.x, lane = tid & 63;
  const int w = tid >> 6, wr = w >> 1, wc = w & 1;
  const int fr = lane & 15, fq = lane >> 4;
#pragma unroll
  for (int mi = 0; mi < 4; ++mi) {
    int mg = bm * 128 + wr * 64 + mi * 16 + fr;
#pragma unroll
    for (int ni = 0; ni < 4; ++ni) {
      int colb = bn * 128 + wc * 64 + ni * 16 + fq * 4;
      float4 b4 = *(const float4*)&bp[colb];
      float4 o;
      o.x = acc[mi][ni][0] + b4.x;
      o.y = acc[mi][ni][1] + b4.y;
      o.z = acc[mi][ni][2] + b4.z;
      o.w = acc[mi][ni][3] + b4.w;
      *(float4*)&out[(size_t)mg * DIM_ + colb] = o;
    }
  }
}

// ---------------- Flash attention v9 (unchanged; verified in R14) ----------------
__global__ __launch_bounds__(256, 2) void attn_kernel(
    const ushort* __restrict__ Qg, const ushort* __restrict__ Kg,
    const ushort* __restrict__ Vtg, const float* __restrict__ rel,
    ushort* __restrict__ outb) {
  __shared__ ushort Ks[4][4096];  // [key][d ^ ((key&7)<<3)]
  __shared__ ushort Vs[4][4096];  // [d][key ^ ((d&7)<<3)]

  const int bid = blockIdx.x;                 // [0,512)
  const int xcd = bid & 7, idx = bid >> 3;
  const int bh = xcd * 4 + (idx >> 4);
  const int q0 = (idx & 15) * 128;
  const int h = bh & 15;
  const int tid = threadIdx.x, lane = tid & 63, w = tid >> 6;
  const int ql = lane & 31, hi = lane >> 5;

  f32x16 biasC;
  {
    float b0 = rel[h * 64 + (ql & 7) * 8 + 0 + 4 * hi] * LOG2E_;
    float b1 = rel[h * 64 + (ql & 7) * 8 + 1 + 4 * hi] * LOG2E_;
    float b2 = rel[h * 64 + (ql & 7) * 8 + 2 + 4 * hi] * LOG2E_;
    float b3 = rel[h * 64 + (ql & 7) * 8 + 3 + 4 * hi] * LOG2E_;
#pragma unroll
    for (int z = 0; z < 16; z += 4) {
      biasC[z] = b0; biasC[z + 1] = b1; biasC[z + 2] = b2; biasC[z + 3] = b3;
    }
  }

  const ushort* qrow = Qg + ((size_t)bh * N_ + q0 + w * 32 + ql) * HD_;
  short8 qf[4];
#pragma unroll
  for (int kk = 0; kk < 4; ++kk)
    qf[kk] = *(const short8*)&qrow[kk * 16 + hi * 8];

  float l = 0.f;
  f32x16 oacc[2] = {};
  f32x16 sA[2], sB[2];

  const int srow = tid >> 3, scol = (tid & 7) * 8;
  const int swsrc = scol ^ ((srow & 7) << 3);
  int kcol[4];
#pragma unroll
  for (int kk = 0; kk < 4; ++kk)
    kcol[kk] = (kk * 16 + hi * 8) ^ ((ql & 7) << 3);

#define STAGE_K(t, bb)                                                              \
  {                                                                                 \
    const size_t kv0 = (size_t)(t) * 64;                                            \
    _Pragma("unroll") for (int c = 0; c < 2; ++c)                                   \
        gload_lds16(Kg + ((size_t)bh * N_ + kv0 + c * 32 + srow) * HD_ + swsrc,     \
                    &Ks[bb][c * 2048 + tid * 8]);                                   \
  }
#define STAGE_V(t, bb)                                                              \
  {                                                                                 \
    const size_t kv0 = (size_t)(t) * 64;                                            \
    _Pragma("unroll") for (int c = 0; c < 2; ++c)                                   \
        gload_lds16(Vtg + ((size_t)(bh * HD_ + c * 32 + srow)) * N_ + kv0 + swsrc,  \
                    &Vs[bb][c * 2048 + tid * 8]);                                   \
  }

#define QKT(S, K_)                                                                  \
  {                                                                                 \
    S[0] = biasC;                                                                   \
    S[1] = biasC;                                                                   \
    __builtin_amdgcn_s_setprio(1);                                                  \
    _Pragma("unroll") for (int kk = 0; kk < 4; ++kk) {                              \
      short8 kf0 = *(const short8*)&(K_)[ql * 64 + kcol[kk]];                       \
      short8 kf1 = *(const short8*)&(K_)[(32 + ql) * 64 + kcol[kk]];                \
      S[0] = __builtin_amdgcn_mfma_f32_32x32x16_bf16(kf0, qf[kk], S[0], 0, 0, 0);   \
      S[1] = __builtin_amdgcn_mfma_f32_32x32x16_bf16(kf1, qf[kk], S[1], 0, 0, 0);   \
    }                                                                               \
    __builtin_amdgcn_s_setprio(0);                                                  \
  }

#define SOFTPV(S, V_)                                                               \
  {                                                                                 \
    float rs_[4] = {0.f, 0.f, 0.f, 0.f};                                            \
    uint32_t c[2][8];                                                               \
    _Pragma("unroll") for (int blk = 0; blk < 2; ++blk) {                           \
      _Pragma("unroll") for (int i = 0; i < 8; ++i) {                               \
        float pa = __builtin_amdgcn_exp2f(S[blk][2 * i]);                           \
        float pb = __builtin_amdgcn_exp2f(S[blk][2 * i + 1]);                       \
        rs_[i & 3] += pa + pb;                                                      \
        c[blk][i] = ((uint32_t)f2bf(pb) << 16) | f2bf(pa);                          \
      }                                                                             \
    }                                                                               \
    float rs = (rs_[0] + rs_[1]) + (rs_[2] + rs_[3]);                               \
    rs += __shfl_xor(rs, 32, 64);                                                   \
    l += rs;                                                                        \
    _Pragma("unroll") for (int blk = 0; blk < 2; ++blk) {                           \
      asm("v_permlane32_swap_b32 %0, %1" : "+v"(c[blk][0]), "+v"(c[blk][2]));       \
      asm("v_permlane32_swap_b32 %0, %1" : "+v"(c[blk][1]), "+v"(c[blk][3]));       \
      asm("v_permlane32_swap_b32 %0, %1" : "+v"(c[blk][4]), "+v"(c[blk][6]));       \
      asm("v_permlane32_swap_b32 %0, %1" : "+v"(c[blk][5]), "+v"(c[blk][7]));       \
    }                                                                               \
    __builtin_amdgcn_s_setprio(1);                                                  \
    _Pragma("unroll") for (int kk = 0; kk < 4; ++kk) {                              \
      union { uint32_t u[4]; short8 s8; } pb_;                                      \
      pb_.u[0] = c[kk >> 1][(kk & 1) * 4 + 0];                                      \
      pb_.u[1] = c[kk >> 1][(kk & 1) * 4 + 1];                                      \
      pb_.u[2] = c[kk >> 1][(kk & 1) * 4 + 2];                                      \
      pb_.u[3] = c[kk >> 1][(kk & 1) * 4 + 3];                                      \
      _Pragma("unroll") for (int db = 0; db < 2; ++db) {                            \
        short8 vf = *(const short8*)&(V_)[(db * 32 + ql) * 64 + kcol[kk]];          \
        oacc[db] = __builtin_amdgcn_mfma_f32_32x32x16_bf16(vf, pb_.s8, oacc[db], 0, 0, 0); \
      }                                                                             \
    }                                                                               \
    __builtin_amdgcn_s_setprio(0);                                                  \
  }

  // prologue: tiles 0,1 into bufs 0,1
  STAGE_K(0, 0); STAGE_V(0, 0);
  STAGE_K(1, 1); STAGE_V(1, 1);
  __syncthreads();

#pragma unroll 1
  for (int tt = 0; tt < 8; ++tt) {
    const int t0 = 4 * tt;
    STAGE_K(t0 + 2, 2); STAGE_V(t0 + 2, 2);
    STAGE_K(t0 + 3, 3); STAGE_V(t0 + 3, 3);
    QKT(sA, Ks[0]);
    QKT(sB, Ks[1]);
    SOFTPV(sA, Vs[0]);
    SOFTPV(sB, Vs[1]);
    __syncthreads();
    if (tt < 7) {
      STAGE_K(t0 + 4, 0); STAGE_V(t0 + 4, 0);
      STAGE_K(t0 + 5, 1); STAGE_V(t0 + 5, 1);
    }
    QKT(sA, Ks[2]);
    QKT(sB, Ks[3]);
    SOFTPV(sA, Vs[2]);
    SOFTPV(sB, Vs[3]);
    __syncthreads();
  }

  // epilogue: O^T[d][q] -> out[b][q][h*64+d]
  const int b = bh >> 4;
  const float invl = 1.0f / l;
  const size_t rowbase = ((size_t)(b * N_ + q0 + w * 32 + ql)) * DIM_ + h * HD_;
#pragma unroll
  for (int db = 0; db < 2; ++db)
#pragma unroll
    for (int g = 0; g < 4; ++g) {
      ushort4 o;
      o.x = f2bf(oacc[db][4 * g + 0] * invl);
      o.y = f2bf(oacc[db][4 * g + 1] * invl);
      o.z = f2bf(oacc[db][4 * g + 2] * invl);
      o.w = f2bf(oacc[db][4 * g + 3] * invl);
      *(ushort4*)&outb[rowbase + db * 32 + 8 * g + 4 * hi] = o;
    }
#undef STAGE_K
#undef STAGE_V
#undef QKT
#undef SOFTPV
}

// ---------------- host launcher ----------------
extern "C" void kernel_launch(void* const* d_in, const int* in_sizes, int n_in,
                              void* d_out, int out_size, void* d_ws, size_t ws_size,
                              hipStream_t stream) {
  const float* x      = (const float*)d_in[0];
  const float* w_qkv  = (const float*)d_in[1];
  const float* b_qkv  = (const float*)d_in[2];
  const float* w_proj = (const float*)d_in[3];
  const float* b_proj = (const float*)d_in[4];
  const float* rel    = (const float*)d_in[5];

  char* ws = (char*)d_ws;
  ushort* xb     = (ushort*)(ws + 0);
  ushort* wqkvb  = (ushort*)(ws + 8388608);
  ushort* wprojb = (ushort*)(ws + 14680064);
  ushort* qb     = (ushort*)(ws + 16777216);
  ushort* kb     = (ushort*)(ws + 25165824);
  ushort* vb     = (ushort*)(ws + 33554432);   // V^T [32][64][2048]
  ushort* aob    = (ushort*)(ws + 41943040);
  (void)in_sizes; (void)n_in; (void)out_size; (void)ws_size;

  cvt_all_kernel<<<8192, 256, 0, stream>>>(
      (const float4*)x, (const float4*)w_qkv, (const float4*)w_proj,
      (ushort4*)xb, (ushort4*)wqkvb, (ushort4*)wprojb);

  gemm_qkv_kernel<<<dim3(24, 32), 256, 0, stream>>>(xb, wqkvb, b_qkv, qb, kb, vb);
  attn_kernel<<<512, 256, 0, stream>>>(qb, kb, vb, rel, aob);
  gemm_proj_kernel<<<256, 256, 0, stream>>>(aob, wprojb, b_proj, (float*)d_out);
}